// Round 2
// baseline (7843.592 us; speedup 1.0000x reference)
//
#include <hip/hip_runtime.h>
#include <hip/hip_bf16.h>
#include <math.h>

// Problem dims (fixed by the reference)
#define RB 64
#define RS 512
#define RE 1024
#define RH 1024
#define BSH ((size_t)RB * RS * RH)

typedef __attribute__((ext_vector_type(8))) __bf16 bf16x8;
typedef __attribute__((ext_vector_type(4))) float  f32x4;

// Build a bf16x8 MFMA fragment from 8 fp32 values (2x float4)
__device__ __forceinline__ bf16x8 cvt8(f32x4 a, f32x4 b) {
    bf16x8 r;
    r[0] = (__bf16)a[0]; r[1] = (__bf16)a[1];
    r[2] = (__bf16)a[2]; r[3] = (__bf16)a[3];
    r[4] = (__bf16)b[0]; r[5] = (__bf16)b[1];
    r[6] = (__bf16)b[2]; r[7] = (__bf16)b[3];
    return r;
}

// ---------------------------------------------------------------------------
// Phase 0: zero the grid-barrier flags (d_ws is re-poisoned to 0xAA each call)
// ---------------------------------------------------------------------------
__global__ void init_flags_k(unsigned* flags) {
    if (threadIdx.x < 64) flags[threadIdx.x] = 0u;
}

// ---------------------------------------------------------------------------
// Phase 1: wx[m,h] = sum_e x[m,e]*W_w[h,e] + W_b[h]  (fp32 in, fp32 out)
// written into d_out's result1 region [B*S, H]; phase 2 reads it there and
// overwrites each element exactly one step after reading it (same lane).
// bf16 conversion happens in registers for the MFMA fragments only.
// Block: 256 thr = 4 waves. Tile: 64 rows x 128 cols. Grid: (H/128, B*S/64)
// (x = n-dim fastest so the 8 blocks sharing an X row-slab launch together).
// ---------------------------------------------------------------------------
__global__ __launch_bounds__(256) void wx_gemm(
    const float* __restrict__ X,
    const float* __restrict__ Ww,
    const float* __restrict__ Wb,
    float* __restrict__ Out)
{
    const int tid  = threadIdx.x;
    const int lane = tid & 63;
    const int wave = tid >> 6;
    const int m0   = blockIdx.y * 64 + wave * 16;
    const int n0   = blockIdx.x * 128;
    const int arow = m0 + (lane & 15);
    const int koff = (lane >> 4) * 8;   // k-offset of this lane's 8 elements

    f32x4 acc[8];
#pragma unroll
    for (int i = 0; i < 8; ++i) acc[i] = (f32x4){0.f, 0.f, 0.f, 0.f};

    const float* xp = X + (size_t)arow * RE + koff;

    for (int kc = 0; kc < RE; kc += 32) {
        const bf16x8 a = cvt8(*reinterpret_cast<const f32x4*>(xp + kc),
                              *reinterpret_cast<const f32x4*>(xp + kc + 4));
#pragma unroll
        for (int nt = 0; nt < 8; ++nt) {
            const float* wp = Ww + (size_t)(n0 + nt * 16 + (lane & 15)) * RE + kc + koff;
            const bf16x8 b = cvt8(*reinterpret_cast<const f32x4*>(wp),
                                  *reinterpret_cast<const f32x4*>(wp + 4));
            acc[nt] = __builtin_amdgcn_mfma_f32_16x16x32_bf16(a, b, acc[nt], 0, 0, 0);
        }
    }

    // C/D layout: col = lane&15, row = (lane>>4)*4 + r   [m89-verified]
    const int col   = lane & 15;
    const int rbase = (lane >> 4) * 4;
#pragma unroll
    for (int nt = 0; nt < 8; ++nt) {
        const int n = n0 + nt * 16 + col;
        const float bias = Wb[n];
#pragma unroll
        for (int r = 0; r < 4; ++r) {
            const int m = m0 + rbase + r;
            Out[(size_t)m * RH + n] = acc[nt][r] + bias;
        }
    }
}

// ---------------------------------------------------------------------------
// Flag-based grid barrier (64 blocks, agent scope => correct across XCDs).
// Each block release-stores its generation into its own slot; wave 0's 64
// lanes poll all 64 slots (one coalesced load per poll, no atomic contention).
// __threadfence (agent seq_cst) emits the L2 writeback / invalidate needed
// for cross-XCD visibility of the ordinary hbuf/Out stores.
// ---------------------------------------------------------------------------
__device__ __forceinline__ void gbar(unsigned* flags, int bid, unsigned target, int tid)
{
    __syncthreads();                       // all waves' stores drained (vmcnt 0)
    if (tid < 64) {
        if (tid == 0) {
            __threadfence();               // release: writeback local L2
            __hip_atomic_store(&flags[bid], target, __ATOMIC_RELAXED,
                               __HIP_MEMORY_SCOPE_AGENT);
        }
        for (;;) {
            unsigned v = __hip_atomic_load(&flags[tid], __ATOMIC_RELAXED,
                                           __HIP_MEMORY_SCOPE_AGENT);
            if (__all((int)(v >= target))) break;
            __builtin_amdgcn_s_sleep(1);
        }
    }
    __syncthreads();
    __threadfence();                       // acquire: invalidate before reading hbuf
}

// ---------------------------------------------------------------------------
// Phase 2: persistent scan. 64 blocks x 256 thr (4 waves). Block n owns
// output columns [16n, 16n+16): its U^T slice lives in 128 VGPRs/lane (bf16)
// for the whole scan. Per step t:
//   t_new[b, cols] = h3_t[b, :] x U^T (MFMA, K=1024, fp32 acc) + U_b[cols]
//   Out[b, t, cols] = t_new                       (fp32)
//   h3_{t+1}[b, cols] = tanh(wx[b, t+1, cols] + t_new) -> hbuf[(t+1)&1] (bf16)
// wx lives in d_out (fp32) and is overwritten by t_new exactly one step after
// the same lane reads it — no cross-block hazard. One grid barrier per step.
// ---------------------------------------------------------------------------
__global__ __launch_bounds__(256) void rnn_scan(
    const float* __restrict__ Uw,
    const float* __restrict__ Ub,
    float* Out,               // [B*S*H] (wx -> result1) then [B*H] t_final
    __bf16* hbuf,             // 2 * B * H bf16, double-buffered h3
    unsigned* flags)          // 64 barrier slots
{
    __shared__ float ubs[16];

    const int tid  = threadIdx.x;
    const int lane = tid & 63;
    const int wave = tid >> 6;
    const int bid  = blockIdx.x;
    const int col0 = bid * 16;

    // --- register-resident U^T slice, bf16-rounded once ---
    // B-frag layout: n = lane&15, k = (lane>>4)*8 + j
    bf16x8 ufr[32];
    {
        const float* up = Uw + (size_t)(col0 + (lane & 15)) * RH + ((lane >> 4) * 8);
#pragma unroll
        for (int kc = 0; kc < 32; ++kc)
            ufr[kc] = cvt8(*reinterpret_cast<const f32x4*>(up + kc * 32),
                           *reinterpret_cast<const f32x4*>(up + kc * 32 + 4));
    }
    if (tid < 16) ubs[tid] = Ub[col0 + tid];

    // --- h3_0 = tanh(wx[:, 0, our cols])  (t0 carry is zero) ---
    for (int i = tid; i < RB * 16; i += 256) {
        const int b = i >> 4, c = i & 15;
        const float w = Out[(size_t)b * RS * RH + col0 + c];
        hbuf[b * RH + col0 + c] = (__bf16)tanhf(w);
    }
    gbar(flags, bid, 1u, tid);

    const int arow  = wave * 16 + (lane & 15);   // batch row for A-frags
    const int koff  = (lane >> 4) * 8;
    const int col   = lane & 15;
    const int rbase = (lane >> 4) * 4;

    for (int t = 0; t < RS; ++t) {
        const __bf16* cur = hbuf + (size_t)(t & 1) * (RB * RH);
        __bf16*       nxt = hbuf + (size_t)((t + 1) & 1) * (RB * RH);
        const __bf16* curp = cur + (size_t)arow * RH + koff;

        f32x4 ac0 = (f32x4){0.f, 0.f, 0.f, 0.f};
        f32x4 ac1 = ac0, ac2 = ac0, ac3 = ac0;

#pragma unroll
        for (int kc = 0; kc < 32; kc += 4) {
            bf16x8 x0 = *reinterpret_cast<const bf16x8*>(curp + (kc + 0) * 32);
            bf16x8 x1 = *reinterpret_cast<const bf16x8*>(curp + (kc + 1) * 32);
            bf16x8 x2 = *reinterpret_cast<const bf16x8*>(curp + (kc + 2) * 32);
            bf16x8 x3 = *reinterpret_cast<const bf16x8*>(curp + (kc + 3) * 32);
            ac0 = __builtin_amdgcn_mfma_f32_16x16x32_bf16(x0, ufr[kc + 0], ac0, 0, 0, 0);
            ac1 = __builtin_amdgcn_mfma_f32_16x16x32_bf16(x1, ufr[kc + 1], ac1, 0, 0, 0);
            ac2 = __builtin_amdgcn_mfma_f32_16x16x32_bf16(x2, ufr[kc + 2], ac2, 0, 0, 0);
            ac3 = __builtin_amdgcn_mfma_f32_16x16x32_bf16(x3, ufr[kc + 3], ac3, 0, 0, 0);
        }
        const f32x4 acc = (ac0 + ac1) + (ac2 + ac3);

#pragma unroll
        for (int r = 0; r < 4; ++r) {
            const int b = wave * 16 + rbase + r;
            const float v = acc[r] + ubs[col];
            const size_t oidx = (size_t)b * RS * RH + (size_t)t * RH + col0 + col;
            if (t == RS - 1) {
                Out[oidx] = v;
                Out[BSH + (size_t)b * RH + col0 + col] = v;    // t_final
            } else {
                // read wx for step t+1 BEFORE overwriting [b,t] (only this same
                // lane ever writes [b,t+1,col], and only at step t+1)
                const float wn = Out[oidx + RH];
                Out[oidx] = v;
                nxt[b * RH + col0 + col] = (__bf16)tanhf(wn + v);
            }
        }
        if (t < RS - 1) gbar(flags, bid, (unsigned)(t + 2), tid);
    }
}

// ---------------------------------------------------------------------------
extern "C" void kernel_launch(void* const* d_in, const int* in_sizes, int n_in,
                              void* d_out, int out_size, void* d_ws, size_t ws_size,
                              hipStream_t stream)
{
    const float* X  = (const float*)d_in[0];   // [B,S,E] fp32
    const float* Ww = (const float*)d_in[1];   // [H,E]   fp32
    const float* Wb = (const float*)d_in[2];   // [H]     fp32
    const float* Uw = (const float*)d_in[3];   // [H,H]   fp32
    const float* Ub = (const float*)d_in[4];   // [H]     fp32
    float* Out = (float*)d_out;                // [B*S*H] result1 + [B*H] t_final

    __bf16* hbuf = (__bf16*)d_ws;              // 2*B*H bf16 = 256 KB
    unsigned* flags = (unsigned*)((char*)d_ws + (size_t)2 * RB * RH * sizeof(__bf16));

    hipLaunchKernelGGL(init_flags_k, dim3(1), dim3(64), 0, stream, flags);
    hipLaunchKernelGGL(wx_gemm, dim3(RH / 128, (RB * RS) / 64), dim3(256), 0, stream,
                       X, Ww, Wb, Out);
    hipLaunchKernelGGL(rnn_scan, dim3(64), dim3(256), 0, stream,
                       Uw, Ub, Out, hbuf, flags);
}

// Round 3
// 7291.326 us; speedup vs baseline: 1.0757x; 1.0757x over previous
//
#include <hip/hip_runtime.h>
#include <hip/hip_bf16.h>
#include <math.h>

// Problem dims (fixed by the reference)
#define RB 64
#define RS 512
#define RE 1024
#define RH 1024
#define BSH ((size_t)RB * RS * RH)

typedef __attribute__((ext_vector_type(8))) __bf16 bf16x8;
typedef __attribute__((ext_vector_type(4))) float  f32x4;

// Build a bf16x8 MFMA fragment from 8 fp32 values (2x float4)
__device__ __forceinline__ bf16x8 cvt8(f32x4 a, f32x4 b) {
    bf16x8 r;
    r[0] = (__bf16)a[0]; r[1] = (__bf16)a[1];
    r[2] = (__bf16)a[2]; r[3] = (__bf16)a[3];
    r[4] = (__bf16)b[0]; r[5] = (__bf16)b[1];
    r[6] = (__bf16)b[2]; r[7] = (__bf16)b[3];
    return r;
}

// L2-bypassing (agent-scope, sc1 -> performed at L3 coherent point) accessors.
// These are how cross-XCD data moves WITHOUT any buffer_wbl2/buffer_inv
// (full-L2 tag-walk) fences — the 13 us/step cost of round 2.
__device__ __forceinline__ bf16x8 ld_frag_agent(const unsigned long long* p) {
    union { unsigned long long u[2]; bf16x8 v; } r;
    r.u[0] = __hip_atomic_load(p,     __ATOMIC_RELAXED, __HIP_MEMORY_SCOPE_AGENT);
    r.u[1] = __hip_atomic_load(p + 1, __ATOMIC_RELAXED, __HIP_MEMORY_SCOPE_AGENT);
    return r.v;
}
__device__ __forceinline__ void st_bf16_agent(__bf16* p, float v) {
    union { __bf16 b; unsigned short s; } u;
    u.b = (__bf16)v;
    __hip_atomic_store(reinterpret_cast<unsigned short*>(p), u.s,
                       __ATOMIC_RELAXED, __HIP_MEMORY_SCOPE_AGENT);
}

// ---------------------------------------------------------------------------
// Phase 0: zero the grid-barrier flags (d_ws is re-poisoned to 0xAA each call)
// ---------------------------------------------------------------------------
__global__ void init_flags_k(unsigned* flags) {
    if (threadIdx.x < 64) flags[threadIdx.x] = 0u;
}

// ---------------------------------------------------------------------------
// Phase 1: wx[m,h] = sum_e x[m,e]*W_w[h,e] + W_b[h]  (fp32 in, fp32 out)
// written into d_out's result1 region [B*S, H]; phase 2 reads it there and
// overwrites each element exactly one step after reading it (same lane).
// ---------------------------------------------------------------------------
__global__ __launch_bounds__(256) void wx_gemm(
    const float* __restrict__ X,
    const float* __restrict__ Ww,
    const float* __restrict__ Wb,
    float* __restrict__ Out)
{
    const int tid  = threadIdx.x;
    const int lane = tid & 63;
    const int wave = tid >> 6;
    const int m0   = blockIdx.y * 64 + wave * 16;
    const int n0   = blockIdx.x * 128;
    const int arow = m0 + (lane & 15);
    const int koff = (lane >> 4) * 8;

    f32x4 acc[8];
#pragma unroll
    for (int i = 0; i < 8; ++i) acc[i] = (f32x4){0.f, 0.f, 0.f, 0.f};

    const float* xp = X + (size_t)arow * RE + koff;

    for (int kc = 0; kc < RE; kc += 32) {
        const bf16x8 a = cvt8(*reinterpret_cast<const f32x4*>(xp + kc),
                              *reinterpret_cast<const f32x4*>(xp + kc + 4));
#pragma unroll
        for (int nt = 0; nt < 8; ++nt) {
            const float* wp = Ww + (size_t)(n0 + nt * 16 + (lane & 15)) * RE + kc + koff;
            const bf16x8 b = cvt8(*reinterpret_cast<const f32x4*>(wp),
                                  *reinterpret_cast<const f32x4*>(wp + 4));
            acc[nt] = __builtin_amdgcn_mfma_f32_16x16x32_bf16(a, b, acc[nt], 0, 0, 0);
        }
    }

    // C/D layout: col = lane&15, row = (lane>>4)*4 + r   [m89-verified]
    const int col   = lane & 15;
    const int rbase = (lane >> 4) * 4;
#pragma unroll
    for (int nt = 0; nt < 8; ++nt) {
        const int n = n0 + nt * 16 + col;
        const float bias = Wb[n];
#pragma unroll
        for (int r = 0; r < 4; ++r) {
            const int m = m0 + rbase + r;
            Out[(size_t)m * RH + n] = acc[nt][r] + bias;
        }
    }
}

// ---------------------------------------------------------------------------
// Fence-free grid barrier. Correctness argument:
//  * All cross-block data (hbuf) is written with sc1 (agent-scope relaxed
//    atomic) stores — write-through to the L3 coherent point, never dirty in
//    a non-coherent per-XCD L2.
//  * __syncthreads() lowers to s_waitcnt vmcnt(0)+s_barrier per wave, so by
//    the time tid 0 stores the flag, every wave's sc1 stores have COMPLETED
//    at L3.
//  * Consumers poll flags with sc1 loads, then read hbuf with sc1 loads —
//    no cached copy can be stale because hbuf never enters L1/L2.
// => no buffer_wbl2 / buffer_inv anywhere.
// ---------------------------------------------------------------------------
__device__ __forceinline__ void gbar(unsigned* flags, int bid, unsigned target, int tid)
{
    __syncthreads();                  // drains each wave's vmcnt (sc1 stores done @L3)
    if (tid == 0)
        __hip_atomic_store(&flags[bid], target, __ATOMIC_RELAXED,
                           __HIP_MEMORY_SCOPE_AGENT);
    if (tid < 64) {
        for (;;) {
            unsigned v = __hip_atomic_load(&flags[tid], __ATOMIC_RELAXED,
                                           __HIP_MEMORY_SCOPE_AGENT);
            if (__all((int)(v >= target))) break;
            __builtin_amdgcn_s_sleep(1);
        }
    }
    __syncthreads();
}

// ---------------------------------------------------------------------------
// Phase 2: persistent scan. 64 blocks x 256 thr (4 waves). Block n owns
// output columns [16n, 16n+16): its U^T slice lives in 128 VGPRs/lane (bf16)
// for the whole scan. One fence-free grid barrier per step.
// ---------------------------------------------------------------------------
__global__ __launch_bounds__(256) void rnn_scan(
    const float* __restrict__ Uw,
    const float* __restrict__ Ub,
    float* Out,               // [B*S*H] (wx -> result1) then [B*H] t_final
    __bf16* hbuf,             // 2 * B * H bf16, double-buffered h3
    unsigned* flags)          // 64 barrier slots
{
    __shared__ float ubs[16];

    const int tid  = threadIdx.x;
    const int lane = tid & 63;
    const int wave = tid >> 6;
    const int bid  = blockIdx.x;
    const int col0 = bid * 16;

    // --- register-resident U^T slice, bf16-rounded once ---
    // B-frag layout: n = lane&15, k = (lane>>4)*8 + j
    bf16x8 ufr[32];
    {
        const float* up = Uw + (size_t)(col0 + (lane & 15)) * RH + ((lane >> 4) * 8);
#pragma unroll
        for (int kc = 0; kc < 32; ++kc)
            ufr[kc] = cvt8(*reinterpret_cast<const f32x4*>(up + kc * 32),
                           *reinterpret_cast<const f32x4*>(up + kc * 32 + 4));
    }
    if (tid < 16) ubs[tid] = Ub[col0 + tid];

    // --- h3_0 = tanh(wx[:, 0, our cols])  (t0 carry is zero) ---
    for (int i = tid; i < RB * 16; i += 256) {
        const int b = i >> 4, c = i & 15;
        const float w = Out[(size_t)b * RS * RH + col0 + c];
        st_bf16_agent(hbuf + b * RH + col0 + c, tanhf(w));
    }
    gbar(flags, bid, 1u, tid);

    const int arow  = wave * 16 + (lane & 15);   // batch row for A-frags
    const int koff  = (lane >> 4) * 8;
    const int col   = lane & 15;
    const int rbase = (lane >> 4) * 4;

    for (int t = 0; t < RS; ++t) {
        const __bf16* cur = hbuf + (size_t)(t & 1) * (RB * RH);
        __bf16*       nxt = hbuf + (size_t)((t + 1) & 1) * (RB * RH);
        // u64 view of this lane's A-frag row (16B-aligned, stride 32 bf16 = 8 u64)
        const unsigned long long* cp = reinterpret_cast<const unsigned long long*>(cur)
                                     + ((size_t)arow * RH + koff) / 4;

        f32x4 ac0 = (f32x4){0.f, 0.f, 0.f, 0.f};
        f32x4 ac1 = ac0, ac2 = ac0, ac3 = ac0;

#pragma unroll
        for (int kc = 0; kc < 32; kc += 4) {
            bf16x8 x0 = ld_frag_agent(cp + (kc + 0) * 8);
            bf16x8 x1 = ld_frag_agent(cp + (kc + 1) * 8);
            bf16x8 x2 = ld_frag_agent(cp + (kc + 2) * 8);
            bf16x8 x3 = ld_frag_agent(cp + (kc + 3) * 8);
            ac0 = __builtin_amdgcn_mfma_f32_16x16x32_bf16(x0, ufr[kc + 0], ac0, 0, 0, 0);
            ac1 = __builtin_amdgcn_mfma_f32_16x16x32_bf16(x1, ufr[kc + 1], ac1, 0, 0, 0);
            ac2 = __builtin_amdgcn_mfma_f32_16x16x32_bf16(x2, ufr[kc + 2], ac2, 0, 0, 0);
            ac3 = __builtin_amdgcn_mfma_f32_16x16x32_bf16(x3, ufr[kc + 3], ac3, 0, 0, 0);
        }
        const f32x4 acc = (ac0 + ac1) + (ac2 + ac3);

#pragma unroll
        for (int r = 0; r < 4; ++r) {
            const int b = wave * 16 + rbase + r;
            const float v = acc[r] + ubs[col];
            const size_t oidx = (size_t)b * RS * RH + (size_t)t * RH + col0 + col;
            if (t == RS - 1) {
                Out[oidx] = v;
                Out[BSH + (size_t)b * RH + col0 + col] = v;    // t_final
            } else {
                // read wx for step t+1 BEFORE overwriting [b,t] (only this same
                // lane ever writes [b,t+1,col], and only at step t+1)
                const float wn = Out[oidx + RH];
                Out[oidx] = v;
                st_bf16_agent(nxt + b * RH + col0 + col, tanhf(wn + v));
            }
        }
        if (t < RS - 1) gbar(flags, bid, (unsigned)(t + 2), tid);
    }
}

// ---------------------------------------------------------------------------
extern "C" void kernel_launch(void* const* d_in, const int* in_sizes, int n_in,
                              void* d_out, int out_size, void* d_ws, size_t ws_size,
                              hipStream_t stream)
{
    const float* X  = (const float*)d_in[0];   // [B,S,E] fp32
    const float* Ww = (const float*)d_in[1];   // [H,E]   fp32
    const float* Wb = (const float*)d_in[2];   // [H]     fp32
    const float* Uw = (const float*)d_in[3];   // [H,H]   fp32
    const float* Ub = (const float*)d_in[4];   // [H]     fp32
    float* Out = (float*)d_out;                // [B*S*H] result1 + [B*H] t_final

    __bf16* hbuf = (__bf16*)d_ws;              // 2*B*H bf16 = 256 KB
    unsigned* flags = (unsigned*)((char*)d_ws + (size_t)2 * RB * RH * sizeof(__bf16));

    hipLaunchKernelGGL(init_flags_k, dim3(1), dim3(64), 0, stream, flags);
    hipLaunchKernelGGL(wx_gemm, dim3(RH / 128, (RB * RS) / 64), dim3(256), 0, stream,
                       X, Ww, Wb, Out);
    hipLaunchKernelGGL(rnn_scan, dim3(64), dim3(256), 0, stream,
                       Uw, Ub, Out, hbuf, flags);
}

// Round 4
// 6043.511 us; speedup vs baseline: 1.2979x; 1.2065x over previous
//
#include <hip/hip_runtime.h>
#include <hip/hip_bf16.h>
#include <math.h>

// Problem dims (fixed by the reference)
#define RB 64
#define RS 512
#define RE 1024
#define RH 1024
#define BSH ((size_t)RB * RS * RH)

typedef __attribute__((ext_vector_type(8))) __bf16 bf16x8;
typedef __attribute__((ext_vector_type(4))) float  f32x4;

// Build a bf16x8 MFMA fragment from 8 fp32 values (2x float4)
__device__ __forceinline__ bf16x8 cvt8(f32x4 a, f32x4 b) {
    bf16x8 r;
    r[0] = (__bf16)a[0]; r[1] = (__bf16)a[1];
    r[2] = (__bf16)a[2]; r[3] = (__bf16)a[3];
    r[4] = (__bf16)b[0]; r[5] = (__bf16)b[1];
    r[6] = (__bf16)b[2]; r[7] = (__bf16)b[3];
    return r;
}

// L2-bypassing (agent-scope => performed at the L3 coherent point) accessors.
// Cross-XCD data moves through these; no buffer_wbl2/buffer_inv fences needed.
__device__ __forceinline__ bf16x8 ld_frag_agent(const unsigned long long* p) {
    union { unsigned long long u[2]; bf16x8 v; } r;
    r.u[0] = __hip_atomic_load(p,     __ATOMIC_RELAXED, __HIP_MEMORY_SCOPE_AGENT);
    r.u[1] = __hip_atomic_load(p + 1, __ATOMIC_RELAXED, __HIP_MEMORY_SCOPE_AGENT);
    return r.v;
}
__device__ __forceinline__ void st_bf16_agent(__bf16* p, float v) {
    union { __bf16 b; unsigned short s; } u;
    u.b = (__bf16)v;
    __hip_atomic_store(reinterpret_cast<unsigned short*>(p), u.s,
                       __ATOMIC_RELAXED, __HIP_MEMORY_SCOPE_AGENT);
}

// ---------------------------------------------------------------------------
// Phase 0: zero the barrier state (d_ws is re-poisoned to 0xAA each call)
// sync[0] = monotonic arrival counter; sync[32] = epoch (separate 128B lines)
// ---------------------------------------------------------------------------
__global__ void init_flags_k(unsigned* sync) {
    if (threadIdx.x < 64) sync[threadIdx.x] = 0u;
}

// ---------------------------------------------------------------------------
// Phase 1: wx[m,h] = sum_e x[m,e]*W_w[h,e] + W_b[h]  (fp32 in, fp32 out)
// written into d_out's result1 region [B*S, H]; phase 2 reads it there and
// overwrites each element exactly one step after reading it (same lane).
// ---------------------------------------------------------------------------
__global__ __launch_bounds__(256) void wx_gemm(
    const float* __restrict__ X,
    const float* __restrict__ Ww,
    const float* __restrict__ Wb,
    float* __restrict__ Out)
{
    const int tid  = threadIdx.x;
    const int lane = tid & 63;
    const int wave = tid >> 6;
    const int m0   = blockIdx.y * 64 + wave * 16;
    const int n0   = blockIdx.x * 128;
    const int arow = m0 + (lane & 15);
    const int koff = (lane >> 4) * 8;

    f32x4 acc[8];
#pragma unroll
    for (int i = 0; i < 8; ++i) acc[i] = (f32x4){0.f, 0.f, 0.f, 0.f};

    const float* xp = X + (size_t)arow * RE + koff;

    for (int kc = 0; kc < RE; kc += 32) {
        const bf16x8 a = cvt8(*reinterpret_cast<const f32x4*>(xp + kc),
                              *reinterpret_cast<const f32x4*>(xp + kc + 4));
#pragma unroll
        for (int nt = 0; nt < 8; ++nt) {
            const float* wp = Ww + (size_t)(n0 + nt * 16 + (lane & 15)) * RE + kc + koff;
            const bf16x8 b = cvt8(*reinterpret_cast<const f32x4*>(wp),
                                  *reinterpret_cast<const f32x4*>(wp + 4));
            acc[nt] = __builtin_amdgcn_mfma_f32_16x16x32_bf16(a, b, acc[nt], 0, 0, 0);
        }
    }

    // C/D layout: col = lane&15, row = (lane>>4)*4 + r   [m89-verified]
    const int col   = lane & 15;
    const int rbase = (lane >> 4) * 4;
#pragma unroll
    for (int nt = 0; nt < 8; ++nt) {
        const int n = n0 + nt * 16 + col;
        const float bias = Wb[n];
#pragma unroll
        for (int r = 0; r < 4; ++r) {
            const int m = m0 + rbase + r;
            Out[(size_t)m * RH + n] = acc[nt][r] + bias;
        }
    }
}

// ---------------------------------------------------------------------------
// Contention-free grid barrier, generation g (1-based, monotonic):
//  * __syncthreads() drains each wave's vmcnt => this block's sc1 data stores
//    have completed at the L3 coherent point before we arrive.
//  * ONE atomicAdd per block on sync[0]. The last arrival (old == 64g-1)
//    publishes sync[32] = g. All other blocks poll sync[32] with a SINGLE
//    lane, paced by s_sleep — 64 pollers on one line instead of round 3's
//    4096 pollers on two lines (the ~12 us/step spin-contention).
// ---------------------------------------------------------------------------
__device__ __forceinline__ void gbar(unsigned* sync, unsigned g, int tid)
{
    __syncthreads();
    if (tid == 0) {
        unsigned old = __hip_atomic_fetch_add(&sync[0], 1u, __ATOMIC_RELAXED,
                                              __HIP_MEMORY_SCOPE_AGENT);
        if (old == 64u * g - 1u) {
            __hip_atomic_store(&sync[32], g, __ATOMIC_RELAXED,
                               __HIP_MEMORY_SCOPE_AGENT);
        } else {
            while (__hip_atomic_load(&sync[32], __ATOMIC_RELAXED,
                                     __HIP_MEMORY_SCOPE_AGENT) < g)
                __builtin_amdgcn_s_sleep(2);
        }
    }
    __syncthreads();
}

// ---------------------------------------------------------------------------
// Phase 2: persistent scan. 64 blocks x 256 thr (4 waves). Block n owns
// output columns [16n, 16n+16): its U^T slice lives in 128 VGPRs/lane (bf16)
// for the whole scan. One contention-free grid barrier per step.
// ---------------------------------------------------------------------------
__global__ __launch_bounds__(256) void rnn_scan(
    const float* __restrict__ Uw,
    const float* __restrict__ Ub,
    float* Out,               // [B*S*H] (wx -> result1) then [B*H] t_final
    __bf16* hbuf,             // 2 * B * H bf16, double-buffered h3
    unsigned* sync)           // barrier state
{
    __shared__ float ubs[16];

    const int tid  = threadIdx.x;
    const int lane = tid & 63;
    const int wave = tid >> 6;
    const int bid  = blockIdx.x;
    const int col0 = bid * 16;

    // --- register-resident U^T slice, bf16-rounded once ---
    // B-frag layout: n = lane&15, k = (lane>>4)*8 + j
    bf16x8 ufr[32];
    {
        const float* up = Uw + (size_t)(col0 + (lane & 15)) * RH + ((lane >> 4) * 8);
#pragma unroll
        for (int kc = 0; kc < 32; ++kc)
            ufr[kc] = cvt8(*reinterpret_cast<const f32x4*>(up + kc * 32),
                           *reinterpret_cast<const f32x4*>(up + kc * 32 + 4));
    }
    if (tid < 16) ubs[tid] = Ub[col0 + tid];

    // --- h3_0 = tanh(wx[:, 0, our cols])  (t0 carry is zero) ---
    for (int i = tid; i < RB * 16; i += 256) {
        const int b = i >> 4, c = i & 15;
        const float w = Out[(size_t)b * RS * RH + col0 + c];
        st_bf16_agent(hbuf + b * RH + col0 + c, tanhf(w));
    }
    gbar(sync, 1u, tid);

    const int arow  = wave * 16 + (lane & 15);   // batch row for A-frags
    const int koff  = (lane >> 4) * 8;
    const int col   = lane & 15;
    const int rbase = (lane >> 4) * 4;

    for (int t = 0; t < RS; ++t) {
        const __bf16* cur = hbuf + (size_t)(t & 1) * (RB * RH);
        __bf16*       nxt = hbuf + (size_t)((t + 1) & 1) * (RB * RH);
        // u64 view of this lane's A-frag row (16B-aligned, stride 32 bf16 = 8 u64)
        const unsigned long long* cp = reinterpret_cast<const unsigned long long*>(cur)
                                     + ((size_t)arow * RH + koff) / 4;

        // Prefetch next step's wx (cold HBM, ~900 cyc) so it overlaps the
        // hbuf loads + MFMA instead of gating the epilogue.
        float wn[4];
        if (t < RS - 1) {
#pragma unroll
            for (int r = 0; r < 4; ++r) {
                const int b = wave * 16 + rbase + r;
                wn[r] = Out[(size_t)b * RS * RH + (size_t)(t + 1) * RH + col0 + col];
            }
        }

        f32x4 ac0 = (f32x4){0.f, 0.f, 0.f, 0.f};
        f32x4 ac1 = ac0, ac2 = ac0, ac3 = ac0;

#pragma unroll
        for (int kc = 0; kc < 32; kc += 4) {
            bf16x8 x0 = ld_frag_agent(cp + (kc + 0) * 8);
            bf16x8 x1 = ld_frag_agent(cp + (kc + 1) * 8);
            bf16x8 x2 = ld_frag_agent(cp + (kc + 2) * 8);
            bf16x8 x3 = ld_frag_agent(cp + (kc + 3) * 8);
            ac0 = __builtin_amdgcn_mfma_f32_16x16x32_bf16(x0, ufr[kc + 0], ac0, 0, 0, 0);
            ac1 = __builtin_amdgcn_mfma_f32_16x16x32_bf16(x1, ufr[kc + 1], ac1, 0, 0, 0);
            ac2 = __builtin_amdgcn_mfma_f32_16x16x32_bf16(x2, ufr[kc + 2], ac2, 0, 0, 0);
            ac3 = __builtin_amdgcn_mfma_f32_16x16x32_bf16(x3, ufr[kc + 3], ac3, 0, 0, 0);
        }
        const f32x4 acc = (ac0 + ac1) + (ac2 + ac3);

#pragma unroll
        for (int r = 0; r < 4; ++r) {
            const int b = wave * 16 + rbase + r;
            const float v = acc[r] + ubs[col];
            const size_t oidx = (size_t)b * RS * RH + (size_t)t * RH + col0 + col;
            if (t == RS - 1) {
                Out[oidx] = v;
                Out[BSH + (size_t)b * RH + col0 + col] = v;    // t_final
            } else {
                Out[oidx] = v;
                st_bf16_agent(nxt + b * RH + col0 + col, tanhf(wn[r] + v));
            }
        }
        if (t < RS - 1) gbar(sync, (unsigned)(t + 2), tid);
    }
}

// ---------------------------------------------------------------------------
extern "C" void kernel_launch(void* const* d_in, const int* in_sizes, int n_in,
                              void* d_out, int out_size, void* d_ws, size_t ws_size,
                              hipStream_t stream)
{
    const float* X  = (const float*)d_in[0];   // [B,S,E] fp32
    const float* Ww = (const float*)d_in[1];   // [H,E]   fp32
    const float* Wb = (const float*)d_in[2];   // [H]     fp32
    const float* Uw = (const float*)d_in[3];   // [H,H]   fp32
    const float* Ub = (const float*)d_in[4];   // [H]     fp32
    float* Out = (float*)d_out;                // [B*S*H] result1 + [B*H] t_final

    __bf16* hbuf = (__bf16*)d_ws;              // 2*B*H bf16 = 256 KB
    unsigned* sync = (unsigned*)((char*)d_ws + (size_t)2 * RB * RH * sizeof(__bf16));

    hipLaunchKernelGGL(init_flags_k, dim3(1), dim3(64), 0, stream, sync);
    hipLaunchKernelGGL(wx_gemm, dim3(RH / 128, (RB * RS) / 64), dim3(256), 0, stream,
                       X, Ww, Wb, Out);
    hipLaunchKernelGGL(rnn_scan, dim3(64), dim3(256), 0, stream,
                       Uw, Ub, Out, hbuf, sync);
}